// Round 1
// baseline (583.822 us; speedup 1.0000x reference)
//
#include <hip/hip_runtime.h>

#define N_NODES 100000
#define N_EDGES 1600000

typedef short s8v __attribute__((ext_vector_type(8)));
typedef float f4v __attribute__((ext_vector_type(4)));
typedef unsigned short us4 __attribute__((ext_vector_type(4)));

__device__ inline unsigned short f2bf(float f) {
    unsigned int u = __float_as_uint(f);
    u += 0x7FFFu + ((u >> 16) & 1u);   // round-to-nearest-even
    return (unsigned short)(u >> 16);
}

__device__ inline float silu_f(float v) {
    return v / (1.0f + __expf(-v));
}

// ---------------------------------------------------------------------------
// Edge kernel: per block, 64 edges.
//   A[e][0:160] = bf16(concat(x[row], x[col], edge_feat))
//   h = silu(A @ We1^T + be1); m = silu(h @ We2^T + be2)
//   atomicAdd into agg[row[e]][:]
// ---------------------------------------------------------------------------
__global__ __launch_bounds__(256) void edge_kernel(
    const float* __restrict__ x, const int* __restrict__ eidx,
    const float* __restrict__ ef,
    const float* __restrict__ We1, const float* __restrict__ be1,
    const float* __restrict__ We2, const float* __restrict__ be2,
    float* agg)
{
    __shared__ unsigned short A[64][168];   // padded stride: bank-uniform b128 reads
    __shared__ unsigned short W1[64][168];  // W1[j][k] = We1[j][k] (B^T layout)
    __shared__ unsigned short H[64][72];
    __shared__ unsigned short W2[64][72];
    __shared__ float B1[64];
    __shared__ float B2[64];
    __shared__ int   RIDX[64];

    const int tid = threadIdx.x;

    // --- stage weights (bf16) ---
    for (int i = tid; i < 64 * 160; i += 256) {
        int j = i / 160, k = i - j * 160;
        W1[j][k] = f2bf(We1[i]);
    }
    for (int i = tid; i < 64 * 64; i += 256) {
        W2[i >> 6][i & 63] = f2bf(We2[i]);
    }
    if (tid < 64) { B1[tid] = be1[tid]; B2[tid] = be2[tid]; }

    // --- stage 64 edges: gather + convert ---
    const int e0  = blockIdx.x * 64;
    const int g   = tid >> 4;      // 16 groups of 16 threads
    const int l16 = tid & 15;
    #pragma unroll
    for (int i = 0; i < 4; ++i) {
        int e  = g + i * 16;       // 0..63
        int ge = e0 + e;
        int r  = eidx[ge];
        int c  = eidx[N_EDGES + ge];
        if (l16 == 0) RIDX[e] = r;

        f4v xr = *(const f4v*)(x + (size_t)r * 64 + l16 * 4);
        us4 ar;
        #pragma unroll
        for (int q = 0; q < 4; ++q) ar[q] = f2bf(xr[q]);
        *(us4*)&A[e][l16 * 4] = ar;

        f4v xc = *(const f4v*)(x + (size_t)c * 64 + l16 * 4);
        us4 ac;
        #pragma unroll
        for (int q = 0; q < 4; ++q) ac[q] = f2bf(xc[q]);
        *(us4*)&A[e][64 + l16 * 4] = ac;

        if (l16 < 8) {
            f4v fe = *(const f4v*)(ef + (size_t)ge * 32 + l16 * 4);
            us4 ae;
            #pragma unroll
            for (int q = 0; q < 4; ++q) ae[q] = f2bf(fe[q]);
            *(us4*)&A[e][128 + l16 * 4] = ae;
        }
    }
    __syncthreads();

    const int lane = tid & 63;
    const int m0   = (tid >> 6) * 16;   // wave's 16 edge rows
    const int lrow = lane & 15;
    const int lkg  = lane >> 4;         // 0..3 k-group

    // --- GEMM1: [64,160] x [160,64] ---
    f4v acc0 = 0, acc1 = 0, acc2 = 0, acc3 = 0;
    #pragma unroll
    for (int s = 0; s < 5; ++s) {
        int k0 = s * 32 + lkg * 8;
        s8v a = *(const s8v*)&A[m0 + lrow][k0];
        s8v b0 = *(const s8v*)&W1[ 0 + lrow][k0];
        s8v b1 = *(const s8v*)&W1[16 + lrow][k0];
        s8v b2 = *(const s8v*)&W1[32 + lrow][k0];
        s8v b3 = *(const s8v*)&W1[48 + lrow][k0];
        acc0 = __builtin_amdgcn_mfma_f32_16x16x32_bf16(a, b0, acc0, 0, 0, 0);
        acc1 = __builtin_amdgcn_mfma_f32_16x16x32_bf16(a, b1, acc1, 0, 0, 0);
        acc2 = __builtin_amdgcn_mfma_f32_16x16x32_bf16(a, b2, acc2, 0, 0, 0);
        acc3 = __builtin_amdgcn_mfma_f32_16x16x32_bf16(a, b3, acc3, 0, 0, 0);
    }
    // silu + write H (wave-local rows: no barrier needed)
    {
        f4v accs[4] = {acc0, acc1, acc2, acc3};
        #pragma unroll
        for (int t = 0; t < 4; ++t) {
            int col = t * 16 + lrow;
            float bias = B1[col];
            #pragma unroll
            for (int r = 0; r < 4; ++r) {
                float v = silu_f(accs[t][r] + bias);
                H[m0 + lkg * 4 + r][col] = f2bf(v);
            }
        }
    }

    // --- GEMM2: [64,64] x [64,64] ---
    f4v c0 = 0, c1 = 0, c2 = 0, c3 = 0;
    #pragma unroll
    for (int s = 0; s < 2; ++s) {
        int k0 = s * 32 + lkg * 8;
        s8v a = *(const s8v*)&H[m0 + lrow][k0];
        s8v b0 = *(const s8v*)&W2[ 0 + lrow][k0];
        s8v b1 = *(const s8v*)&W2[16 + lrow][k0];
        s8v b2 = *(const s8v*)&W2[32 + lrow][k0];
        s8v b3 = *(const s8v*)&W2[48 + lrow][k0];
        c0 = __builtin_amdgcn_mfma_f32_16x16x32_bf16(a, b0, c0, 0, 0, 0);
        c1 = __builtin_amdgcn_mfma_f32_16x16x32_bf16(a, b1, c1, 0, 0, 0);
        c2 = __builtin_amdgcn_mfma_f32_16x16x32_bf16(a, b2, c2, 0, 0, 0);
        c3 = __builtin_amdgcn_mfma_f32_16x16x32_bf16(a, b3, c3, 0, 0, 0);
    }
    // silu + atomic scatter into agg
    {
        f4v cs[4] = {c0, c1, c2, c3};
        #pragma unroll
        for (int r = 0; r < 4; ++r) {
            int node = RIDX[m0 + lkg * 4 + r];
            float* dst = agg + (size_t)node * 64;
            #pragma unroll
            for (int t = 0; t < 4; ++t) {
                int col = t * 16 + lrow;
                float v = silu_f(cs[t][r] + B2[col]);
                atomicAdd(dst + col, v);
            }
        }
    }
}

// ---------------------------------------------------------------------------
// Node kernel: per block, 64 nodes. Reads agg in-place from `io` (own rows
// only, before syncthreads), writes out to same rows afterwards.
//   h2 = silu(concat(x, agg) @ Wn1^T + bn1); out = h2 @ Wn2^T + bn2
// ---------------------------------------------------------------------------
__global__ __launch_bounds__(256) void node_kernel(
    const float* __restrict__ x,
    const float* __restrict__ Wn1, const float* __restrict__ bn1,
    const float* __restrict__ Wn2, const float* __restrict__ bn2,
    float* io)
{
    __shared__ unsigned short A[64][136];
    __shared__ unsigned short W1[64][136];
    __shared__ unsigned short H[64][72];
    __shared__ unsigned short W2[64][72];
    __shared__ float B1[64];
    __shared__ float B2[64];

    const int tid = threadIdx.x;

    for (int i = tid; i < 64 * 128; i += 256) {
        W1[i >> 7][i & 127] = f2bf(Wn1[i]);
    }
    for (int i = tid; i < 64 * 64; i += 256) {
        W2[i >> 6][i & 63] = f2bf(Wn2[i]);
    }
    if (tid < 64) { B1[tid] = bn1[tid]; B2[tid] = bn2[tid]; }

    const int n0  = blockIdx.x * 64;
    const int g   = tid >> 4;
    const int l16 = tid & 15;
    #pragma unroll
    for (int i = 0; i < 4; ++i) {
        int e = g + i * 16;
        int n = n0 + e;
        if (n >= N_NODES) n = N_NODES - 1;   // clamp: reads valid, stores guarded

        f4v xv = *(const f4v*)(x + (size_t)n * 64 + l16 * 4);
        us4 av;
        #pragma unroll
        for (int q = 0; q < 4; ++q) av[q] = f2bf(xv[q]);
        *(us4*)&A[e][l16 * 4] = av;

        f4v gv = *(const f4v*)(io + (size_t)n * 64 + l16 * 4);
        us4 ag;
        #pragma unroll
        for (int q = 0; q < 4; ++q) ag[q] = f2bf(gv[q]);
        *(us4*)&A[e][64 + l16 * 4] = ag;
    }
    __syncthreads();

    const int lane = tid & 63;
    const int m0   = (tid >> 6) * 16;
    const int lrow = lane & 15;
    const int lkg  = lane >> 4;

    // GEMM1: [64,128] x [128,64]
    f4v acc0 = 0, acc1 = 0, acc2 = 0, acc3 = 0;
    #pragma unroll
    for (int s = 0; s < 4; ++s) {
        int k0 = s * 32 + lkg * 8;
        s8v a = *(const s8v*)&A[m0 + lrow][k0];
        s8v b0 = *(const s8v*)&W1[ 0 + lrow][k0];
        s8v b1 = *(const s8v*)&W1[16 + lrow][k0];
        s8v b2 = *(const s8v*)&W1[32 + lrow][k0];
        s8v b3 = *(const s8v*)&W1[48 + lrow][k0];
        acc0 = __builtin_amdgcn_mfma_f32_16x16x32_bf16(a, b0, acc0, 0, 0, 0);
        acc1 = __builtin_amdgcn_mfma_f32_16x16x32_bf16(a, b1, acc1, 0, 0, 0);
        acc2 = __builtin_amdgcn_mfma_f32_16x16x32_bf16(a, b2, acc2, 0, 0, 0);
        acc3 = __builtin_amdgcn_mfma_f32_16x16x32_bf16(a, b3, acc3, 0, 0, 0);
    }
    {
        f4v accs[4] = {acc0, acc1, acc2, acc3};
        #pragma unroll
        for (int t = 0; t < 4; ++t) {
            int col = t * 16 + lrow;
            float bias = B1[col];
            #pragma unroll
            for (int r = 0; r < 4; ++r) {
                float v = silu_f(accs[t][r] + bias);
                H[m0 + lkg * 4 + r][col] = f2bf(v);
            }
        }
    }

    // GEMM2: [64,64] x [64,64]  (no activation; +bn2)
    f4v c0 = 0, c1 = 0, c2 = 0, c3 = 0;
    #pragma unroll
    for (int s = 0; s < 2; ++s) {
        int k0 = s * 32 + lkg * 8;
        s8v a = *(const s8v*)&H[m0 + lrow][k0];
        s8v b0 = *(const s8v*)&W2[ 0 + lrow][k0];
        s8v b1 = *(const s8v*)&W2[16 + lrow][k0];
        s8v b2 = *(const s8v*)&W2[32 + lrow][k0];
        s8v b3 = *(const s8v*)&W2[48 + lrow][k0];
        c0 = __builtin_amdgcn_mfma_f32_16x16x32_bf16(a, b0, c0, 0, 0, 0);
        c1 = __builtin_amdgcn_mfma_f32_16x16x32_bf16(a, b1, c1, 0, 0, 0);
        c2 = __builtin_amdgcn_mfma_f32_16x16x32_bf16(a, b2, c2, 0, 0, 0);
        c3 = __builtin_amdgcn_mfma_f32_16x16x32_bf16(a, b3, c3, 0, 0, 0);
    }
    {
        f4v cs[4] = {c0, c1, c2, c3};
        #pragma unroll
        for (int r = 0; r < 4; ++r) {
            int n = n0 + m0 + lkg * 4 + r;
            if (n < N_NODES) {
                float* dst = io + (size_t)n * 64;
                #pragma unroll
                for (int t = 0; t < 4; ++t) {
                    int col = t * 16 + lrow;
                    dst[col] = cs[t][r] + B2[col];
                }
            }
        }
    }
}

extern "C" void kernel_launch(void* const* d_in, const int* in_sizes, int n_in,
                              void* d_out, int out_size, void* d_ws, size_t ws_size,
                              hipStream_t stream) {
    const float* x    = (const float*)d_in[0];
    const int*   eidx = (const int*)  d_in[1];
    const float* ef   = (const float*)d_in[2];
    const float* We1  = (const float*)d_in[3];
    const float* be1  = (const float*)d_in[4];
    const float* We2  = (const float*)d_in[5];
    const float* be2  = (const float*)d_in[6];
    const float* Wn1  = (const float*)d_in[7];
    const float* bn1  = (const float*)d_in[8];
    const float* Wn2  = (const float*)d_in[9];
    const float* bn2  = (const float*)d_in[10];
    float* out = (float*)d_out;

    // d_out doubles as the agg accumulator (exactly N_NODES*64 f32)
    hipMemsetAsync(d_out, 0, (size_t)N_NODES * 64 * sizeof(float), stream);

    edge_kernel<<<N_EDGES / 64, 256, 0, stream>>>(x, eidx, ef, We1, be1, We2, be2, out);
    node_kernel<<<(N_NODES + 63) / 64, 256, 0, stream>>>(x, Wn1, bn1, Wn2, bn2, out);
}

// Round 2
// 458.256 us; speedup vs baseline: 1.2740x; 1.2740x over previous
//
#include <hip/hip_runtime.h>

#define N_NODES 100000
#define N_EDGES 1600000

typedef short s8v __attribute__((ext_vector_type(8)));
typedef float f4v __attribute__((ext_vector_type(4)));
typedef unsigned short us4 __attribute__((ext_vector_type(4)));

__device__ inline unsigned short f2bf(float f) {
    unsigned int u = __float_as_uint(f);
    u += 0x7FFFu + ((u >> 16) & 1u);   // round-to-nearest-even
    return (unsigned short)(u >> 16);
}

__device__ inline float silu_f(float v) {
    return v / (1.0f + __expf(-v));
}

// ---------------------------------------------------------------------------
// Prepass: x (f32, [N,64]) -> bf16 copy in workspace. 12.8 MB.
// ---------------------------------------------------------------------------
__global__ __launch_bounds__(256) void x2bf_kernel(const float* __restrict__ x,
                                                   unsigned short* __restrict__ xb)
{
    const int total = N_NODES * 64 / 4;   // 1.6M quads
    for (int i = blockIdx.x * blockDim.x + threadIdx.x; i < total;
         i += gridDim.x * blockDim.x) {
        f4v v = *(const f4v*)(x + (size_t)i * 4);
        us4 o;
        #pragma unroll
        for (int q = 0; q < 4; ++q) o[q] = f2bf(v[q]);
        *(us4*)(xb + (size_t)i * 4) = o;
    }
}

// ---------------------------------------------------------------------------
// Edge kernel v2: barrier-free waves, fragment-major weights in LDS.
// Each wave processes independent groups of 16 edges (grid-stride).
//   A-fragments gathered straight from global (x_bf16 + edge_feat f32->bf16)
//   GEMM1 [16,160]x[160,64] -> silu -> H (wave-private LDS, frag-major)
//   GEMM2 [16,64]x[64,64]  -> silu -> atomicAdd scatter into agg
// ---------------------------------------------------------------------------
__global__ __launch_bounds__(256, 4) void edge_kernel(
    const unsigned short* __restrict__ xb, const int* __restrict__ eidx,
    const float* __restrict__ ef,
    const float* __restrict__ We1, const float* __restrict__ be1,
    const float* __restrict__ We2, const float* __restrict__ be2,
    float* agg)
{
    // fragment-major: frag f = t*5+s (GEMM1) holds per-lane 8 bf16 at [f*64+lane]*8
    __shared__ unsigned short W1L[64 * 160];   // 20480 B
    __shared__ unsigned short W2L[64 * 64];    //  8192 B
    __shared__ unsigned short HL[4][2][64][8]; //  8192 B

    const int tid = threadIdx.x;

    // --- stage weights once per block, fragment-major, bf16 ---
    for (int i = tid; i < 64 * 160; i += 256) {
        int row = i / 160;
        int k   = i - row * 160;
        int t = row >> 4, lr = row & 15;
        int s = k >> 5, kg = (k >> 3) & 3, j = k & 7;
        W1L[(((t * 5 + s) * 64) + (kg * 16 + lr)) * 8 + j] = f2bf(We1[i]);
    }
    for (int i = tid; i < 64 * 64; i += 256) {
        int row = i >> 6;
        int k   = i & 63;
        int t = row >> 4, lr = row & 15;
        int s = k >> 5, kg = (k >> 3) & 3, j = k & 7;
        W2L[(((t * 2 + s) * 64) + (kg * 16 + lr)) * 8 + j] = f2bf(We2[i]);
    }
    __syncthreads();   // only barrier in the kernel

    const int lane = tid & 63;
    const int wv   = tid >> 6;
    const int lrow = lane & 15;
    const int lkg  = lane >> 4;

    // biases in registers: lane needs col = t*16+lrow
    float b1f[4], b2f[4];
    #pragma unroll
    for (int t = 0; t < 4; ++t) {
        b1f[t] = be1[t * 16 + lrow];
        b2f[t] = be2[t * 16 + lrow];
    }

    const int n_groups = N_EDGES / 16;                 // 100000
    const int wave_id  = blockIdx.x * 4 + wv;
    const int n_waves  = gridDim.x * 4;

    for (int grp = wave_id; grp < n_groups; grp += n_waves) {
        const int e0 = grp * 16;

        // edge endpoints for this lane's row (lanes 16..63 mirror 0..15)
        const int r = eidx[e0 + lrow];
        const int c = eidx[N_EDGES + e0 + lrow];

        // --- gather A-fragments directly from global ---
        s8v afr[5];
        afr[0] = *(const s8v*)(xb + (size_t)r * 64 + lkg * 8);
        afr[1] = *(const s8v*)(xb + (size_t)r * 64 + 32 + lkg * 8);
        afr[2] = *(const s8v*)(xb + (size_t)c * 64 + lkg * 8);
        afr[3] = *(const s8v*)(xb + (size_t)c * 64 + 32 + lkg * 8);
        {
            const float* ep = ef + (size_t)(e0 + lrow) * 32 + lkg * 8;
            f4v elo = *(const f4v*)ep;
            f4v ehi = *(const f4v*)(ep + 4);
            s8v a4;
            #pragma unroll
            for (int q = 0; q < 4; ++q) {
                a4[q]     = (short)f2bf(elo[q]);
                a4[q + 4] = (short)f2bf(ehi[q]);
            }
            afr[4] = a4;
        }

        // --- GEMM1: [16,160] x [160,64] ---
        f4v acc[4] = {f4v(0), f4v(0), f4v(0), f4v(0)};
        #pragma unroll
        for (int s = 0; s < 5; ++s) {
            #pragma unroll
            for (int t = 0; t < 4; ++t) {
                s8v b = *(const s8v*)&W1L[((t * 5 + s) * 64 + lane) * 8];
                acc[t] = __builtin_amdgcn_mfma_f32_16x16x32_bf16(afr[s], b, acc[t], 0, 0, 0);
            }
        }

        // --- silu -> H (wave-private, fragment-major for GEMM2 A-reads) ---
        #pragma unroll
        for (int t = 0; t < 4; ++t) {
            const int col = t * 16 + lrow;
            const int s   = col >> 5;
            const int lsub = (col & 31) >> 3;
            const int j   = col & 7;
            #pragma unroll
            for (int rr = 0; rr < 4; ++rr) {
                float v = silu_f(acc[t][rr] + b1f[t]);
                HL[wv][s][lsub * 16 + (lkg * 4 + rr)][j] = f2bf(v);
            }
        }
        // wave-local LDS write->read: compiler inserts lgkmcnt wait

        // --- GEMM2: [16,64] x [64,64] ---
        s8v h0 = *(const s8v*)&HL[wv][0][lane][0];
        s8v h1 = *(const s8v*)&HL[wv][1][lane][0];
        f4v c2[4] = {f4v(0), f4v(0), f4v(0), f4v(0)};
        #pragma unroll
        for (int t = 0; t < 4; ++t) {
            s8v b0 = *(const s8v*)&W2L[((t * 2 + 0) * 64 + lane) * 8];
            s8v b1 = *(const s8v*)&W2L[((t * 2 + 1) * 64 + lane) * 8];
            c2[t] = __builtin_amdgcn_mfma_f32_16x16x32_bf16(h0, b0, c2[t], 0, 0, 0);
            c2[t] = __builtin_amdgcn_mfma_f32_16x16x32_bf16(h1, b1, c2[t], 0, 0, 0);
        }

        // --- silu -> atomic scatter ---
        #pragma unroll
        for (int rr = 0; rr < 4; ++rr) {
            const int node = __shfl(r, lkg * 4 + rr);
            float* dst = agg + (size_t)node * 64;
            #pragma unroll
            for (int t = 0; t < 4; ++t) {
                float v = silu_f(c2[t][rr] + b2f[t]);
                atomicAdd(dst + t * 16 + lrow, v);
            }
        }
    }
}

// ---------------------------------------------------------------------------
// Node kernel: per block, 64 nodes (unchanged from round 0 — minor cost).
// ---------------------------------------------------------------------------
__global__ __launch_bounds__(256) void node_kernel(
    const float* __restrict__ x,
    const float* __restrict__ Wn1, const float* __restrict__ bn1,
    const float* __restrict__ Wn2, const float* __restrict__ bn2,
    float* io)
{
    __shared__ unsigned short A[64][136];
    __shared__ unsigned short W1[64][136];
    __shared__ unsigned short H[64][72];
    __shared__ unsigned short W2[64][72];
    __shared__ float B1[64];
    __shared__ float B2[64];

    const int tid = threadIdx.x;

    for (int i = tid; i < 64 * 128; i += 256) {
        W1[i >> 7][i & 127] = f2bf(Wn1[i]);
    }
    for (int i = tid; i < 64 * 64; i += 256) {
        W2[i >> 6][i & 63] = f2bf(Wn2[i]);
    }
    if (tid < 64) { B1[tid] = bn1[tid]; B2[tid] = bn2[tid]; }

    const int n0  = blockIdx.x * 64;
    const int g   = tid >> 4;
    const int l16 = tid & 15;
    #pragma unroll
    for (int i = 0; i < 4; ++i) {
        int e = g + i * 16;
        int n = n0 + e;
        if (n >= N_NODES) n = N_NODES - 1;

        f4v xv = *(const f4v*)(x + (size_t)n * 64 + l16 * 4);
        us4 av;
        #pragma unroll
        for (int q = 0; q < 4; ++q) av[q] = f2bf(xv[q]);
        *(us4*)&A[e][l16 * 4] = av;

        f4v gv = *(const f4v*)(io + (size_t)n * 64 + l16 * 4);
        us4 ag;
        #pragma unroll
        for (int q = 0; q < 4; ++q) ag[q] = f2bf(gv[q]);
        *(us4*)&A[e][64 + l16 * 4] = ag;
    }
    __syncthreads();

    const int lane = tid & 63;
    const int m0   = (tid >> 6) * 16;
    const int lrow = lane & 15;
    const int lkg  = lane >> 4;

    f4v acc0 = 0, acc1 = 0, acc2 = 0, acc3 = 0;
    #pragma unroll
    for (int s = 0; s < 4; ++s) {
        int k0 = s * 32 + lkg * 8;
        s8v a = *(const s8v*)&A[m0 + lrow][k0];
        s8v b0 = *(const s8v*)&W1[ 0 + lrow][k0];
        s8v b1 = *(const s8v*)&W1[16 + lrow][k0];
        s8v b2 = *(const s8v*)&W1[32 + lrow][k0];
        s8v b3 = *(const s8v*)&W1[48 + lrow][k0];
        acc0 = __builtin_amdgcn_mfma_f32_16x16x32_bf16(a, b0, acc0, 0, 0, 0);
        acc1 = __builtin_amdgcn_mfma_f32_16x16x32_bf16(a, b1, acc1, 0, 0, 0);
        acc2 = __builtin_amdgcn_mfma_f32_16x16x32_bf16(a, b2, acc2, 0, 0, 0);
        acc3 = __builtin_amdgcn_mfma_f32_16x16x32_bf16(a, b3, acc3, 0, 0, 0);
    }
    {
        f4v accs[4] = {acc0, acc1, acc2, acc3};
        #pragma unroll
        for (int t = 0; t < 4; ++t) {
            int col = t * 16 + lrow;
            float bias = B1[col];
            #pragma unroll
            for (int r = 0; r < 4; ++r) {
                float v = silu_f(accs[t][r] + bias);
                H[m0 + lkg * 4 + r][col] = f2bf(v);
            }
        }
    }

    f4v c0 = 0, c1 = 0, c2 = 0, c3 = 0;
    #pragma unroll
    for (int s = 0; s < 2; ++s) {
        int k0 = s * 32 + lkg * 8;
        s8v a = *(const s8v*)&H[m0 + lrow][k0];
        s8v b0 = *(const s8v*)&W2[ 0 + lrow][k0];
        s8v b1 = *(const s8v*)&W2[16 + lrow][k0];
        s8v b2 = *(const s8v*)&W2[32 + lrow][k0];
        s8v b3 = *(const s8v*)&W2[48 + lrow][k0];
        c0 = __builtin_amdgcn_mfma_f32_16x16x32_bf16(a, b0, c0, 0, 0, 0);
        c1 = __builtin_amdgcn_mfma_f32_16x16x32_bf16(a, b1, c1, 0, 0, 0);
        c2 = __builtin_amdgcn_mfma_f32_16x16x32_bf16(a, b2, c2, 0, 0, 0);
        c3 = __builtin_amdgcn_mfma_f32_16x16x32_bf16(a, b3, c3, 0, 0, 0);
    }
    {
        f4v cs[4] = {c0, c1, c2, c3};
        #pragma unroll
        for (int r = 0; r < 4; ++r) {
            int n = n0 + m0 + lkg * 4 + r;
            if (n < N_NODES) {
                float* dst = io + (size_t)n * 64;
                #pragma unroll
                for (int t = 0; t < 4; ++t) {
                    int col = t * 16 + lrow;
                    dst[col] = cs[t][r] + B2[col];
                }
            }
        }
    }
}

extern "C" void kernel_launch(void* const* d_in, const int* in_sizes, int n_in,
                              void* d_out, int out_size, void* d_ws, size_t ws_size,
                              hipStream_t stream) {
    const float* x    = (const float*)d_in[0];
    const int*   eidx = (const int*)  d_in[1];
    const float* ef   = (const float*)d_in[2];
    const float* We1  = (const float*)d_in[3];
    const float* be1  = (const float*)d_in[4];
    const float* We2  = (const float*)d_in[5];
    const float* be2  = (const float*)d_in[6];
    const float* Wn1  = (const float*)d_in[7];
    const float* bn1  = (const float*)d_in[8];
    const float* Wn2  = (const float*)d_in[9];
    const float* bn2  = (const float*)d_in[10];
    float* out = (float*)d_out;

    unsigned short* xb = (unsigned short*)d_ws;   // 12.8 MB bf16 copy of x

    // d_out doubles as the agg accumulator (exactly N_NODES*64 f32)
    hipMemsetAsync(d_out, 0, (size_t)N_NODES * 64 * sizeof(float), stream);

    x2bf_kernel<<<1024, 256, 0, stream>>>(x, xb);
    edge_kernel<<<1024, 256, 0, stream>>>(xb, eidx, ef, We1, be1, We2, be2, out);
    node_kernel<<<(N_NODES + 63) / 64, 256, 0, stream>>>(x, Wn1, bn1, Wn2, bn2, out);
}